// Round 11
// baseline (237.659 us; speedup 1.0000x reference)
//
#include <hip/hip_runtime.h>
#include <hip/hip_bf16.h>

#define B_  2
#define N_  512
#define M_  512
#define H_  256
#define NH_ 8
#define DH_ 32

typedef __attribute__((ext_vector_type(4))) float f32x4;
typedef __attribute__((ext_vector_type(8))) short bf16x8;

static __device__ __forceinline__ float fast_exp2(float x) { return __builtin_amdgcn_exp2f(x); }
static __device__ __forceinline__ float fast_rcp(float x)  { return __builtin_amdgcn_rcpf(x); }

// fp32 -> bf16 bits, round-to-nearest-even (inputs are finite)
static __device__ __forceinline__ unsigned short f2b(float f) {
    unsigned int u = __float_as_uint(f);
    u += 0x7fffu + ((u >> 16) & 1u);
    return (unsigned short)(u >> 16);
}

// LDS-only barrier (no vmcnt drain). Works ONLY with both conditions:
// (a) all vmem the next phase consumes is register-prefetched BEFORE the
//     store burst, and (b) loads+stores per tile per wave <= 63 so the
//     compiler can encode a counted vmcnt that skips the stores.
// R8 violated (b) (128 scalar stores), R9 used hard __syncthreads (vmcnt(0)).
// This round: 17 loads + 32 dwordx4 stores = 49 ops -> vmcnt(32) steady state.
#define SOFT_BARRIER() asm volatile("s_waitcnt lgkmcnt(0)\n\ts_barrier" ::: "memory")

// ---------------------------------------------------------------------------
// K1: fused input projections. blockIdx.y selects {q@Wq, k@Wk, k@Wv}.
// which==1 additionally emits kp as bf16 (kpb) for addattn's register prefetch.
// ---------------------------------------------------------------------------
#define TM 8
__global__ __launch_bounds__(256) void proj3_kernel(const float* __restrict__ Q,
                                                    const float* __restrict__ K,
                                                    const float* __restrict__ Wq,
                                                    const float* __restrict__ Wk,
                                                    const float* __restrict__ Wv,
                                                    float* __restrict__ qp,
                                                    float* __restrict__ kp,
                                                    float* __restrict__ vv,
                                                    unsigned short* __restrict__ kpb) {
    const int which = blockIdx.y;
    const float* X = (which == 0) ? Q : K;
    const float* W = (which == 0) ? Wq : (which == 1) ? Wk : Wv;
    float* Y = (which == 0) ? qp : (which == 1) ? kp : vv;

    __shared__ __align__(16) float xs[TM][H_];
    const int t = threadIdx.x;
    const int r0 = blockIdx.x * TM;
    for (int idx = t; idx < TM * H_; idx += 256)
        xs[idx >> 8][idx & 255] = X[(size_t)(r0 + (idx >> 8)) * H_ + (idx & 255)];
    __syncthreads();

    float acc[TM];
#pragma unroll
    for (int r = 0; r < TM; ++r) acc[r] = 0.f;

    const float* wrow = W + (size_t)t * H_;
    for (int k = 0; k < H_; k += 4) {
        float4 w4 = *(const float4*)(wrow + k);
#pragma unroll
        for (int r = 0; r < TM; ++r) {
            acc[r] += w4.x * xs[r][k] + w4.y * xs[r][k + 1] +
                      w4.z * xs[r][k + 2] + w4.w * xs[r][k + 3];
        }
    }
#pragma unroll
    for (int r = 0; r < TM; ++r) {
        Y[(size_t)(r0 + r) * H_ + t] = acc[r];
        if (which == 1) kpb[(size_t)(r0 + r) * H_ + t] = f2b(acc[r]);
    }
}

// single-projection variant for the output GEMM
__global__ __launch_bounds__(256) void proj_kernel(const float* __restrict__ X,
                                                   const float* __restrict__ W,
                                                   float* __restrict__ Y) {
    __shared__ __align__(16) float xs[TM][H_];
    const int t = threadIdx.x;
    const int r0 = blockIdx.x * TM;
    for (int idx = t; idx < TM * H_; idx += 256)
        xs[idx >> 8][idx & 255] = X[(size_t)(r0 + (idx >> 8)) * H_ + (idx & 255)];
    __syncthreads();

    float acc[TM];
#pragma unroll
    for (int r = 0; r < TM; ++r) acc[r] = 0.f;

    const float* wrow = W + (size_t)t * H_;
    for (int k = 0; k < H_; k += 4) {
        float4 w4 = *(const float4*)(wrow + k);
#pragma unroll
        for (int r = 0; r < TM; ++r) {
            acc[r] += w4.x * xs[r][k] + w4.y * xs[r][k + 1] +
                      w4.z * xs[r][k + 2] + w4.w * xs[r][k + 3];
        }
    }
#pragma unroll
    for (int r = 0; r < TM; ++r) Y[(size_t)(r0 + r) * H_ + t] = acc[r];
}

// ---------------------------------------------------------------------------
// K3: multi-head dot-product attention (flash-style over j-tiles of 128)
// ---------------------------------------------------------------------------
__global__ __launch_bounds__(256) void mh_attn_kernel(const float* __restrict__ qp,
                                                      const float* __restrict__ kp,
                                                      const float* __restrict__ vv,
                                                      float* __restrict__ ctx) {
    __shared__ __align__(16) float ks[128][36];
    __shared__ __align__(16) float vs[128][36];
    const int t = threadIdx.x;
    const int bh = blockIdx.x;
    const int b = bh >> 3, head = bh & 7;
    const int i0 = blockIdx.y * 32;
    const int r = t >> 3, sub = t & 7;
    const int i = i0 + r;
    const float rs = 0.17677669529663687f;   // 1/sqrt(32)
    const float C = 1.4426950408889634f;     // log2(e)

    const float* qptr = qp + ((size_t)(b * N_ + i)) * H_ + head * DH_;
    float4 q[8];
#pragma unroll
    for (int d = 0; d < 8; ++d) q[d] = *(const float4*)(qptr + d * 4);

    float mrun = -1e30f, lrun = 0.f;
    float4 o[8];
#pragma unroll
    for (int d = 0; d < 8; ++d) o[d] = make_float4(0.f, 0.f, 0.f, 0.f);

    for (int jt = 0; jt < 4; ++jt) {
        __syncthreads();
#pragma unroll
        for (int cc = 0; cc < 4; ++cc) {
            int cIdx = t + cc * 256;
            int jr = cIdx >> 3, d4 = cIdx & 7;
            size_t gofs = ((size_t)(b * M_ + jt * 128 + jr)) * H_ + head * DH_ + d4 * 4;
            *(float4*)(&ks[jr][d4 * 4]) = *(const float4*)(kp + gofs);
            *(float4*)(&vs[jr][d4 * 4]) = *(const float4*)(vv + gofs);
        }
        __syncthreads();

        float s16[16];
#pragma unroll
        for (int jj = 0; jj < 16; ++jj) {
            const float* kr = ks[sub + jj * 8];
            float a = 0.f;
#pragma unroll
            for (int d = 0; d < 8; ++d) {
                float4 kv = *(const float4*)(kr + d * 4);
                a += q[d].x * kv.x + q[d].y * kv.y + q[d].z * kv.z + q[d].w * kv.w;
            }
            s16[jj] = a * rs;
        }
        float tm = s16[0];
#pragma unroll
        for (int jj = 1; jj < 16; ++jj) tm = fmaxf(tm, s16[jj]);
        float mnew = fmaxf(mrun, tm);
        float corr = fast_exp2((mrun - mnew) * C);
        lrun *= corr;
#pragma unroll
        for (int d = 0; d < 8; ++d) {
            o[d].x *= corr; o[d].y *= corr; o[d].z *= corr; o[d].w *= corr;
        }
        mrun = mnew;
#pragma unroll
        for (int jj = 0; jj < 16; ++jj) {
            float p = fast_exp2((s16[jj] - mrun) * C);
            lrun += p;
            const float* vr = vs[sub + jj * 8];
#pragma unroll
            for (int d = 0; d < 8; ++d) {
                float4 vx = *(const float4*)(vr + d * 4);
                o[d].x = __builtin_fmaf(p, vx.x, o[d].x);
                o[d].y = __builtin_fmaf(p, vx.y, o[d].y);
                o[d].z = __builtin_fmaf(p, vx.z, o[d].z);
                o[d].w = __builtin_fmaf(p, vx.w, o[d].w);
            }
        }
    }

#pragma unroll
    for (int mask = 1; mask < 8; mask <<= 1) {
        float om = __shfl_xor(mrun, mask, 64);
        float ol = __shfl_xor(lrun, mask, 64);
        float Mx = fmaxf(mrun, om);
        float fa = fast_exp2((mrun - Mx) * C);
        float fb = fast_exp2((om - Mx) * C);
        lrun = lrun * fa + ol * fb;
#pragma unroll
        for (int d = 0; d < 8; ++d) {
            float ox = __shfl_xor(o[d].x, mask, 64);
            float oy = __shfl_xor(o[d].y, mask, 64);
            float oz = __shfl_xor(o[d].z, mask, 64);
            float ow = __shfl_xor(o[d].w, mask, 64);
            o[d].x = o[d].x * fa + ox * fb;
            o[d].y = o[d].y * fa + oy * fb;
            o[d].z = o[d].z * fa + oz * fb;
            o[d].w = o[d].w * fa + ow * fb;
        }
        mrun = Mx;
    }
    float inv = fast_rcp(lrun);
    float4 r4 = make_float4(0.f, 0.f, 0.f, 0.f);
#pragma unroll
    for (int d = 0; d < 8; ++d) if (sub == d) r4 = o[d];
    r4.x *= inv; r4.y *= inv; r4.z *= inv; r4.w *= inv;
    *(float4*)(ctx + ((size_t)(b * N_ + i)) * H_ + head * DH_ + sub * 4) = r4;
}

// ---------------------------------------------------------------------------
// K2: additive-attention branch — the missing matrix cell:
// SOFT barriers + load-free k-loop (full kp-slice bf16 register prefetch +
// q register prefetch issued BEFORE the stores) + 32 chunked dwordx4 stores.
// vmem ops per tile per wave = 17 loads + 32 stores = 49 <= 63, so the
// compiler's waitcnt before the next tile's register uses is vmcnt(32):
// it waits on the prefetch loads only and the 32 stores drain under the
// whole next k-loop. Wv is staged pre-scaled by log2(e) so the softmax is
// exp2(acc) directly.
// ---------------------------------------------------------------------------
#define BM2 256
#define TILES_TOTAL 2048
#define K2_BLOCKS 256

__global__ __launch_bounds__(512, 2) void addattn_kernel(const float* __restrict__ qp,
                                                         const unsigned short* __restrict__ kpb,
                                                         const float* __restrict__ Wv,
                                                         float* __restrict__ attn) {
    __shared__ __align__(16) unsigned short wv_s[H_ * H_];  // 128 KB swizzled bf16 (pre-scaled by C)
    __shared__ __align__(16) float qrow[H_];                // 1 KB

    const int t = threadIdx.x;
    const int lane = t & 63;
    const int w = t >> 6;        // wave 0..7
    const int li = lane & 15;
    const int kq = lane >> 4;    // 0..3
    const int wrow0 = w * 32;
    const float C = 1.4426950408889634f;
    const float L2E2 = 2.885390081777927f;   // 2*log2(e)

    // ---- stage C*Wv as bf16; 16B-slot XOR swizzle keyed on (o>>2)&15 ----
#pragma unroll
    for (int itr = 0; itr < 16; ++itr) {
        int sIdx = t + itr * 512;          // 16B-slot index 0..8191
        int o = sIdx >> 5;
        int slot = sIdx & 31;
        const float* src = Wv + (size_t)o * H_ + slot * 8;
        float4 a = *(const float4*)(src);
        float4 bq = *(const float4*)(src + 4);
        union { unsigned short us[8]; uint4 v; } pk;
        pk.us[0] = f2b(a.x * C);  pk.us[1] = f2b(a.y * C);  pk.us[2] = f2b(a.z * C);  pk.us[3] = f2b(a.w * C);
        pk.us[4] = f2b(bq.x * C); pk.us[5] = f2b(bq.y * C); pk.us[6] = f2b(bq.z * C); pk.us[7] = f2b(bq.w * C);
        int dslot = slot ^ ((o >> 2) & 15);
        *(uint4*)(wv_s + (size_t)o * 256 + dslot * 8) = pk.v;
    }

    int tile = blockIdx.x;

    uint4 kpre[2][8];                 // next tile's kp slice, bf16 (32 VGPR)
    f32x4 qnext = (f32x4){0.f, 0.f, 0.f, 0.f};

    // prologue: prefetch the FIRST tile's kp + q (no stores outstanding yet)
    {
        const int b = tile >> 10;
        const int i = (tile >> 1) & (N_ - 1);
        const int j0 = (tile & 1) * BM2;
#pragma unroll
        for (int rf = 0; rf < 2; ++rf) {
            const unsigned short* kr = kpb + (size_t)(b * M_ + j0 + wrow0 + rf * 16 + li) * H_ + kq * 8;
#pragma unroll
            for (int kk = 0; kk < 8; ++kk)
                kpre[rf][kk] = *(const uint4*)(kr + kk * 32);
        }
        if (t < 64) qnext = *(const f32x4*)(qp + ((size_t)(b * N_ + i)) * H_ + t * 4);
    }

    for (; tile < TILES_TOTAL; tile += K2_BLOCKS) {
        SOFT_BARRIER();   // prior tile done reading qrow (LDS only; stores keep draining)
        if (t < 64) *(f32x4*)(qrow + t * 4) = qnext;
        SOFT_BARRIER();   // qrow (and, on 1st iter, wv_s) visible

        f32x4 acc[2][16];
#pragma unroll
        for (int rf = 0; rf < 2; ++rf)
#pragma unroll
            for (int c = 0; c < 16; ++c) acc[rf][c] = (f32x4){0.f, 0.f, 0.f, 0.f};

        // ---- k-loop: registers + LDS only (NO global loads) ----
#pragma unroll
        for (int kk = 0; kk < 8; ++kk) {
            f32x4 qs0 = *(const f32x4*)(qrow + kk * 32 + kq * 8);
            f32x4 qs1 = *(const f32x4*)(qrow + kk * 32 + kq * 8 + 4);

            bf16x8 afr[2];
#pragma unroll
            for (int rf = 0; rf < 2; ++rf) {
                const uint4 kv = kpre[rf][kk];
                float xin[8];
                xin[0] = __uint_as_float(kv.x << 16)          + qs0[0];
                xin[1] = __uint_as_float(kv.x & 0xffff0000u)  + qs0[1];
                xin[2] = __uint_as_float(kv.y << 16)          + qs0[2];
                xin[3] = __uint_as_float(kv.y & 0xffff0000u)  + qs0[3];
                xin[4] = __uint_as_float(kv.z << 16)          + qs1[0];
                xin[5] = __uint_as_float(kv.z & 0xffff0000u)  + qs1[1];
                xin[6] = __uint_as_float(kv.w << 16)          + qs1[2];
                xin[7] = __uint_as_float(kv.w & 0xffff0000u)  + qs1[3];
                union { unsigned short us[8]; bf16x8 v; } au;
#pragma unroll
                for (int e = 0; e < 8; ++e) {
                    float e2 = fast_exp2(xin[e] * L2E2);
                    float th = __builtin_fmaf(-2.0f, fast_rcp(e2 + 1.0f), 1.0f);
                    au.us[e] = f2b(th);
                }
                afr[rf] = au.v;
            }

            const int rslot = (kk * 4 + kq) ^ li;     // swizzled k-slot (key = li)
#pragma unroll
            for (int c = 0; c < 16; ++c) {
                const int o = (c >> 2) * 64 + li * 4 + (c & 3);  // chunked col map
                bf16x8 bfr = *(const bf16x8*)(wv_s + (size_t)o * 256 + rslot * 8);
                acc[0][c] = __builtin_amdgcn_mfma_f32_16x16x32_bf16(afr[0], bfr, acc[0][c], 0, 0, 0);
                acc[1][c] = __builtin_amdgcn_mfma_f32_16x16x32_bf16(afr[1], bfr, acc[1][c], 0, 0, 0);
            }
        }

        // ---- prefetch next tile's ENTIRE kp slice + q row BEFORE stores ----
        if (tile + K2_BLOCKS < TILES_TOTAL) {
            const int nt = tile + K2_BLOCKS;
            const int nb = nt >> 10;
            const int ni = (nt >> 1) & (N_ - 1);
            const int nj0 = (nt & 1) * BM2;
#pragma unroll
            for (int rf = 0; rf < 2; ++rf) {
                const unsigned short* kr = kpb + (size_t)(nb * M_ + nj0 + wrow0 + rf * 16 + li) * H_ + kq * 8;
#pragma unroll
                for (int kk = 0; kk < 8; ++kk)
                    kpre[rf][kk] = *(const uint4*)(kr + kk * 32);
            }
            if (t < 64) qnext = *(const f32x4*)(qp + ((size_t)(nb * N_ + ni)) * H_ + t * 4);
        }
        __builtin_amdgcn_sched_barrier(0);   // pin: prefetch loads issue before stores

        // ---- epilogue: softmax (Wv pre-scaled by C -> p = exp2(acc));
        // 32 chunked dwordx4 stores per wave (full 64B lines) ----
        const size_t prow = (size_t)tile * BM2;
#pragma unroll
        for (int rf = 0; rf < 2; ++rf) {
#pragma unroll
            for (int v = 0; v < 4; ++v) {
                float rsum = 0.f;
#pragma unroll
                for (int c = 0; c < 16; ++c) {
                    float e = fast_exp2(acc[rf][c][v]);
                    acc[rf][c][v] = e;
                    rsum += e;
                }
#pragma unroll
                for (int mask = 1; mask < 16; mask <<= 1)
                    rsum += __shfl_xor(rsum, mask, 64);
                const float inv = fast_rcp(rsum);
                const int jl = wrow0 + rf * 16 + kq * 4 + v;
                float* dst = attn + (prow + jl) * (size_t)H_ + li * 4;
#pragma unroll
                for (int chunk = 0; chunk < 4; ++chunk) {
                    f32x4 s4 = (f32x4){acc[rf][chunk * 4][v] * inv,
                                       acc[rf][chunk * 4 + 1][v] * inv,
                                       acc[rf][chunk * 4 + 2][v] * inv,
                                       acc[rf][chunk * 4 + 3][v] * inv};
                    __builtin_nontemporal_store(s4, (f32x4*)(dst + chunk * 64));
                }
            }
        }
    }
}

// ---------------------------------------------------------------------------
extern "C" void kernel_launch(void* const* d_in, const int* in_sizes, int n_in,
                              void* d_out, int out_size, void* d_ws, size_t ws_size,
                              hipStream_t stream) {
    (void)in_sizes; (void)n_in; (void)out_size; (void)ws_size;
    const float* queries = (const float*)d_in[0];
    const float* keys    = (const float*)d_in[1];
    const float* Wq = (const float*)d_in[3];
    const float* Wk = (const float*)d_in[4];
    const float* Wv = (const float*)d_in[5];
    const float* Wo = (const float*)d_in[6];

    float* out0 = (float*)d_out;                               // (B, n, H)
    float* attn = (float*)d_out + (size_t)B_ * N_ * H_;        // (B, n, m, H)

    float* ws  = (float*)d_ws;
    float* qp  = ws;                           // 262144 f
    float* kp  = ws + 262144;                  // 262144 f
    float* vv  = ws + 524288;                  // 262144 f
    float* ctx = ws + 786432;                  // 262144 f
    unsigned short* kpb = (unsigned short*)(ws + 1048576);  // 262144 bf16 (512 KB)

    proj3_kernel<<<dim3(128, 3), dim3(256), 0, stream>>>(queries, keys, Wq, Wk, Wv, qp, kp, vv, kpb);
    mh_attn_kernel<<<dim3(16, 16), dim3(256), 0, stream>>>(qp, kp, vv, ctx);
    proj_kernel<<<dim3(128), dim3(256), 0, stream>>>(ctx, Wo, out0);
    addattn_kernel<<<dim3(K2_BLOCKS), dim3(512), 0, stream>>>(qp, kpb, Wv, attn);
}

// Round 12
// 220.035 us; speedup vs baseline: 1.0801x; 1.0801x over previous
//
#include <hip/hip_runtime.h>
#include <hip/hip_bf16.h>

#define B_  2
#define N_  512
#define M_  512
#define H_  256
#define NH_ 8
#define DH_ 32

typedef __attribute__((ext_vector_type(4))) float f32x4;
typedef __attribute__((ext_vector_type(8))) short bf16x8;

static __device__ __forceinline__ float fast_exp2(float x) { return __builtin_amdgcn_exp2f(x); }
static __device__ __forceinline__ float fast_rcp(float x)  { return __builtin_amdgcn_rcpf(x); }

// fp32 -> bf16 bits, round-to-nearest-even (inputs are finite)
static __device__ __forceinline__ unsigned short f2b(float f) {
    unsigned int u = __float_as_uint(f);
    u += 0x7fffu + ((u >> 16) & 1u);
    return (unsigned short)(u >> 16);
}

// ---------------------------------------------------------------------------
// K1: fused input projections. blockIdx.y selects {q@Wq, k@Wk, k@Wv}.
// ---------------------------------------------------------------------------
#define TM 8
__global__ __launch_bounds__(256) void proj3_kernel(const float* __restrict__ Q,
                                                    const float* __restrict__ K,
                                                    const float* __restrict__ Wq,
                                                    const float* __restrict__ Wk,
                                                    const float* __restrict__ Wv,
                                                    float* __restrict__ qp,
                                                    float* __restrict__ kp,
                                                    float* __restrict__ vv) {
    const int which = blockIdx.y;
    const float* X = (which == 0) ? Q : K;
    const float* W = (which == 0) ? Wq : (which == 1) ? Wk : Wv;
    float* Y = (which == 0) ? qp : (which == 1) ? kp : vv;

    __shared__ __align__(16) float xs[TM][H_];
    const int t = threadIdx.x;
    const int r0 = blockIdx.x * TM;
    for (int idx = t; idx < TM * H_; idx += 256)
        xs[idx >> 8][idx & 255] = X[(size_t)(r0 + (idx >> 8)) * H_ + (idx & 255)];
    __syncthreads();

    float acc[TM];
#pragma unroll
    for (int r = 0; r < TM; ++r) acc[r] = 0.f;

    const float* wrow = W + (size_t)t * H_;
    for (int k = 0; k < H_; k += 4) {
        float4 w4 = *(const float4*)(wrow + k);
#pragma unroll
        for (int r = 0; r < TM; ++r) {
            acc[r] += w4.x * xs[r][k] + w4.y * xs[r][k + 1] +
                      w4.z * xs[r][k + 2] + w4.w * xs[r][k + 3];
        }
    }
#pragma unroll
    for (int r = 0; r < TM; ++r) Y[(size_t)(r0 + r) * H_ + t] = acc[r];
}

// single-projection variant for the output GEMM
__global__ __launch_bounds__(256) void proj_kernel(const float* __restrict__ X,
                                                   const float* __restrict__ W,
                                                   float* __restrict__ Y) {
    __shared__ __align__(16) float xs[TM][H_];
    const int t = threadIdx.x;
    const int r0 = blockIdx.x * TM;
    for (int idx = t; idx < TM * H_; idx += 256)
        xs[idx >> 8][idx & 255] = X[(size_t)(r0 + (idx >> 8)) * H_ + (idx & 255)];
    __syncthreads();

    float acc[TM];
#pragma unroll
    for (int r = 0; r < TM; ++r) acc[r] = 0.f;

    const float* wrow = W + (size_t)t * H_;
    for (int k = 0; k < H_; k += 4) {
        float4 w4 = *(const float4*)(wrow + k);
#pragma unroll
        for (int r = 0; r < TM; ++r) {
            acc[r] += w4.x * xs[r][k] + w4.y * xs[r][k + 1] +
                      w4.z * xs[r][k + 2] + w4.w * xs[r][k + 3];
        }
    }
#pragma unroll
    for (int r = 0; r < TM; ++r) Y[(size_t)(r0 + r) * H_ + t] = acc[r];
}

// ---------------------------------------------------------------------------
// K3: multi-head dot-product attention (flash-style over j-tiles of 128)
// ---------------------------------------------------------------------------
__global__ __launch_bounds__(256) void mh_attn_kernel(const float* __restrict__ qp,
                                                      const float* __restrict__ kp,
                                                      const float* __restrict__ vv,
                                                      float* __restrict__ ctx) {
    __shared__ __align__(16) float ks[128][36];
    __shared__ __align__(16) float vs[128][36];
    const int t = threadIdx.x;
    const int bh = blockIdx.x;
    const int b = bh >> 3, head = bh & 7;
    const int i0 = blockIdx.y * 32;
    const int r = t >> 3, sub = t & 7;
    const int i = i0 + r;
    const float rs = 0.17677669529663687f;   // 1/sqrt(32)
    const float C = 1.4426950408889634f;     // log2(e)

    const float* qptr = qp + ((size_t)(b * N_ + i)) * H_ + head * DH_;
    float4 q[8];
#pragma unroll
    for (int d = 0; d < 8; ++d) q[d] = *(const float4*)(qptr + d * 4);

    float mrun = -1e30f, lrun = 0.f;
    float4 o[8];
#pragma unroll
    for (int d = 0; d < 8; ++d) o[d] = make_float4(0.f, 0.f, 0.f, 0.f);

    for (int jt = 0; jt < 4; ++jt) {
        __syncthreads();
#pragma unroll
        for (int cc = 0; cc < 4; ++cc) {
            int cIdx = t + cc * 256;
            int jr = cIdx >> 3, d4 = cIdx & 7;
            size_t gofs = ((size_t)(b * M_ + jt * 128 + jr)) * H_ + head * DH_ + d4 * 4;
            *(float4*)(&ks[jr][d4 * 4]) = *(const float4*)(kp + gofs);
            *(float4*)(&vs[jr][d4 * 4]) = *(const float4*)(vv + gofs);
        }
        __syncthreads();

        float s16[16];
#pragma unroll
        for (int jj = 0; jj < 16; ++jj) {
            const float* kr = ks[sub + jj * 8];
            float a = 0.f;
#pragma unroll
            for (int d = 0; d < 8; ++d) {
                float4 kv = *(const float4*)(kr + d * 4);
                a += q[d].x * kv.x + q[d].y * kv.y + q[d].z * kv.z + q[d].w * kv.w;
            }
            s16[jj] = a * rs;
        }
        float tm = s16[0];
#pragma unroll
        for (int jj = 1; jj < 16; ++jj) tm = fmaxf(tm, s16[jj]);
        float mnew = fmaxf(mrun, tm);
        float corr = fast_exp2((mrun - mnew) * C);
        lrun *= corr;
#pragma unroll
        for (int d = 0; d < 8; ++d) {
            o[d].x *= corr; o[d].y *= corr; o[d].z *= corr; o[d].w *= corr;
        }
        mrun = mnew;
#pragma unroll
        for (int jj = 0; jj < 16; ++jj) {
            float p = fast_exp2((s16[jj] - mrun) * C);
            lrun += p;
            const float* vr = vs[sub + jj * 8];
#pragma unroll
            for (int d = 0; d < 8; ++d) {
                float4 vx = *(const float4*)(vr + d * 4);
                o[d].x = __builtin_fmaf(p, vx.x, o[d].x);
                o[d].y = __builtin_fmaf(p, vx.y, o[d].y);
                o[d].z = __builtin_fmaf(p, vx.z, o[d].z);
                o[d].w = __builtin_fmaf(p, vx.w, o[d].w);
            }
        }
    }

#pragma unroll
    for (int mask = 1; mask < 8; mask <<= 1) {
        float om = __shfl_xor(mrun, mask, 64);
        float ol = __shfl_xor(lrun, mask, 64);
        float Mx = fmaxf(mrun, om);
        float fa = fast_exp2((mrun - Mx) * C);
        float fb = fast_exp2((om - Mx) * C);
        lrun = lrun * fa + ol * fb;
#pragma unroll
        for (int d = 0; d < 8; ++d) {
            float ox = __shfl_xor(o[d].x, mask, 64);
            float oy = __shfl_xor(o[d].y, mask, 64);
            float oz = __shfl_xor(o[d].z, mask, 64);
            float ow = __shfl_xor(o[d].w, mask, 64);
            o[d].x = o[d].x * fa + ox * fb;
            o[d].y = o[d].y * fa + oy * fb;
            o[d].z = o[d].z * fa + oz * fb;
            o[d].w = o[d].w * fa + ow * fb;
        }
        mrun = Mx;
    }
    float inv = fast_rcp(lrun);
    float4 r4 = make_float4(0.f, 0.f, 0.f, 0.f);
#pragma unroll
    for (int d = 0; d < 8; ++d) if (sub == d) r4 = o[d];
    r4.x *= inv; r4.y *= inv; r4.z *= inv; r4.w *= inv;
    *(float4*)(ctx + ((size_t)(b * N_ + i)) * H_ + head * DH_ + sub * 4) = r4;
}

// ---------------------------------------------------------------------------
// K2: additive-attention branch — R6 structure (the 220.8 µs winner: hard
// barriers, lockstep phases, in-loop kk prefetch, cross-tile kk=0 prefetch,
// scalar dword nt stores, o=c*16+li map) with two constant-fold micro-opts:
//  (a) qrow staged pre-scaled by 2*log2(e)  -> k-loop xin = fma(kp,L2E2,qs)
//  (b) Wv staged pre-scaled by log2(e)      -> epilogue p = exp2(acc)
// Both validated numerically in earlier rounds (R5/R11, absmax unchanged).
// ---------------------------------------------------------------------------
#define BM2 256
#define TILES_TOTAL 2048
#define K2_BLOCKS 256

__global__ __launch_bounds__(512, 2) void addattn_kernel(const float* __restrict__ qp,
                                                         const float* __restrict__ kp,
                                                         const float* __restrict__ Wv,
                                                         float* __restrict__ attn) {
    __shared__ __align__(16) unsigned short wv_s[H_ * H_];  // 128 KB swizzled bf16 (pre-scaled by C)
    __shared__ __align__(16) float qrow[H_];                // 1 KB (pre-scaled by 2*log2e)

    const int t = threadIdx.x;
    const int lane = t & 63;
    const int w = t >> 6;        // wave 0..7
    const int li = lane & 15;
    const int kq = lane >> 4;    // 0..3
    const int wrow0 = w * 32;
    const float C = 1.4426950408889634f;
    const float L2E2 = 2.885390081777927f;   // 2*log2(e)

    // ---- stage C*Wv as bf16 with 16B-slot XOR swizzle (key = o&15) ----
#pragma unroll
    for (int it = 0; it < 16; ++it) {
        int sIdx = t + it * 512;          // 16B-slot index 0..8191
        int o = sIdx >> 5;
        int slot = sIdx & 31;
        const float* src = Wv + (size_t)o * H_ + slot * 8;
        float4 a = *(const float4*)(src);
        float4 bq = *(const float4*)(src + 4);
        union { unsigned short us[8]; uint4 v; } pk;
        pk.us[0] = f2b(a.x * C);  pk.us[1] = f2b(a.y * C);  pk.us[2] = f2b(a.z * C);  pk.us[3] = f2b(a.w * C);
        pk.us[4] = f2b(bq.x * C); pk.us[5] = f2b(bq.y * C); pk.us[6] = f2b(bq.z * C); pk.us[7] = f2b(bq.w * C);
        int dslot = slot ^ (o & 15);
        *(uint4*)(wv_s + (size_t)o * 256 + dslot * 8) = pk.v;
    }

    int tile = blockIdx.x;

    // preload first tile's kp slices (kk = 0)
    float4 cur[2][2];
    {
        const int b = tile >> 10;
        const int j0 = (tile & 1) * BM2;
#pragma unroll
        for (int rf = 0; rf < 2; ++rf) {
            const int jl = wrow0 + rf * 16 + li;
            const float* kr = kp + ((size_t)(b * M_ + j0 + jl)) * H_ + kq * 8;
            cur[rf][0] = *(const float4*)(kr);
            cur[rf][1] = *(const float4*)(kr + 4);
        }
    }

    for (; tile < TILES_TOTAL; tile += K2_BLOCKS) {
        const int b = tile >> 10;                 // tile / 1024
        const int i = (tile >> 1) & (N_ - 1);
        const int j0 = (tile & 1) * BM2;

        __syncthreads();   // prior tile done with qrow; store queue drains here
        if (t < 64) {
            f32x4 qv = *(const f32x4*)(qp + ((size_t)(b * N_ + i)) * H_ + t * 4);
            qv *= L2E2;
            *(f32x4*)(qrow + t * 4) = qv;
        }
        __syncthreads();   // qrow (and, on 1st iter, wv_s) visible

        f32x4 acc[2][16];
#pragma unroll
        for (int rf = 0; rf < 2; ++rf)
#pragma unroll
            for (int c = 0; c < 16; ++c) acc[rf][c] = (f32x4){0.f, 0.f, 0.f, 0.f};

#pragma unroll
        for (int kk = 0; kk < 8; ++kk) {
            float4 nxt[2][2];
            if (kk < 7) {
#pragma unroll
                for (int rf = 0; rf < 2; ++rf) {
                    const int jl = wrow0 + rf * 16 + li;
                    const float* kr = kp + ((size_t)(b * M_ + j0 + jl)) * H_ + (kk + 1) * 32 + kq * 8;
                    nxt[rf][0] = *(const float4*)(kr);
                    nxt[rf][1] = *(const float4*)(kr + 4);
                }
            }
            f32x4 qs0 = *(const f32x4*)(qrow + kk * 32 + kq * 8);
            f32x4 qs1 = *(const f32x4*)(qrow + kk * 32 + kq * 8 + 4);

            bf16x8 afr[2];
#pragma unroll
            for (int rf = 0; rf < 2; ++rf) {
                float xin[8] = {
                    __builtin_fmaf(cur[rf][0].x, L2E2, qs0[0]),
                    __builtin_fmaf(cur[rf][0].y, L2E2, qs0[1]),
                    __builtin_fmaf(cur[rf][0].z, L2E2, qs0[2]),
                    __builtin_fmaf(cur[rf][0].w, L2E2, qs0[3]),
                    __builtin_fmaf(cur[rf][1].x, L2E2, qs1[0]),
                    __builtin_fmaf(cur[rf][1].y, L2E2, qs1[1]),
                    __builtin_fmaf(cur[rf][1].z, L2E2, qs1[2]),
                    __builtin_fmaf(cur[rf][1].w, L2E2, qs1[3])};
                union { unsigned short us[8]; bf16x8 v; } au;
#pragma unroll
                for (int e = 0; e < 8; ++e) {
                    float e2 = fast_exp2(xin[e]);
                    float th = __builtin_fmaf(-2.0f, fast_rcp(e2 + 1.0f), 1.0f);
                    au.us[e] = f2b(th);
                }
                afr[rf] = au.v;
            }

#pragma unroll
            for (int c = 0; c < 16; ++c) {
                const int o = c * 16 + li;
                const int slot = (kk * 4 + kq) ^ (o & 15);
                bf16x8 bfr = *(const bf16x8*)(wv_s + (size_t)o * 256 + slot * 8);
                acc[0][c] = __builtin_amdgcn_mfma_f32_16x16x32_bf16(afr[0], bfr, acc[0][c], 0, 0, 0);
                acc[1][c] = __builtin_amdgcn_mfma_f32_16x16x32_bf16(afr[1], bfr, acc[1][c], 0, 0, 0);
            }
            if (kk < 7) {
#pragma unroll
                for (int rf = 0; rf < 2; ++rf) { cur[rf][0] = nxt[rf][0]; cur[rf][1] = nxt[rf][1]; }
            }
        }

        // prefetch next tile's kp (kk=0) BEFORE the epilogue stores
        if (tile + K2_BLOCKS < TILES_TOTAL) {
            const int nt = tile + K2_BLOCKS;
            const int nb = nt >> 10;
            const int nj0 = (nt & 1) * BM2;
#pragma unroll
            for (int rf = 0; rf < 2; ++rf) {
                const int jl = wrow0 + rf * 16 + li;
                const float* kr = kp + ((size_t)(nb * M_ + nj0 + jl)) * H_ + kq * 8;
                cur[rf][0] = *(const float4*)(kr);
                cur[rf][1] = *(const float4*)(kr + 4);
            }
        }

        // ---- epilogue: softmax over the 256 cols of each row (Wv pre-scaled
        // by C -> p = exp2(acc) directly; bounded scores, no max subtraction),
        // scalar dword nt stores (full 64B line per 16-lane group) ----
        const size_t prow = (size_t)tile * BM2;
#pragma unroll
        for (int rf = 0; rf < 2; ++rf) {
#pragma unroll
            for (int v = 0; v < 4; ++v) {
                float p[16];
                float rsum = 0.f;
#pragma unroll
                for (int c = 0; c < 16; ++c) {
                    p[c] = fast_exp2(acc[rf][c][v]);
                    rsum += p[c];
                }
#pragma unroll
                for (int mask = 1; mask < 16; mask <<= 1)
                    rsum += __shfl_xor(rsum, mask, 64);
                const float inv = fast_rcp(rsum);
                const int jl = wrow0 + rf * 16 + kq * 4 + v;
                float* dst = attn + (prow + jl) * (size_t)H_ + li;
#pragma unroll
                for (int c = 0; c < 16; ++c)
                    __builtin_nontemporal_store(p[c] * inv, dst + c * 16);
            }
        }
    }
}

// ---------------------------------------------------------------------------
extern "C" void kernel_launch(void* const* d_in, const int* in_sizes, int n_in,
                              void* d_out, int out_size, void* d_ws, size_t ws_size,
                              hipStream_t stream) {
    (void)in_sizes; (void)n_in; (void)out_size; (void)ws_size;
    const float* queries = (const float*)d_in[0];
    const float* keys    = (const float*)d_in[1];
    const float* Wq = (const float*)d_in[3];
    const float* Wk = (const float*)d_in[4];
    const float* Wv = (const float*)d_in[5];
    const float* Wo = (const float*)d_in[6];

    float* out0 = (float*)d_out;                               // (B, n, H)
    float* attn = (float*)d_out + (size_t)B_ * N_ * H_;        // (B, n, m, H)

    float* ws  = (float*)d_ws;
    float* qp  = ws;                 // 262144 f
    float* kp  = ws + 262144;        // 262144 f
    float* vv  = ws + 524288;        // 262144 f
    float* ctx = ws + 786432;        // 262144 f

    proj3_kernel<<<dim3(128, 3), dim3(256), 0, stream>>>(queries, keys, Wq, Wk, Wv, qp, kp, vv);
    mh_attn_kernel<<<dim3(16, 16), dim3(256), 0, stream>>>(qp, kp, vv, ctx);
    proj_kernel<<<dim3(128), dim3(256), 0, stream>>>(ctx, Wo, out0);
    addattn_kernel<<<dim3(K2_BLOCKS), dim3(512), 0, stream>>>(qp, kp, Wv, attn);
}

// Round 13
// 219.665 us; speedup vs baseline: 1.0819x; 1.0017x over previous
//
#include <hip/hip_runtime.h>
#include <hip/hip_bf16.h>

#define B_  2
#define N_  512
#define M_  512
#define H_  256
#define NH_ 8
#define DH_ 32

typedef __attribute__((ext_vector_type(4))) float f32x4;
typedef __attribute__((ext_vector_type(8))) short bf16x8;

static __device__ __forceinline__ float fast_exp2(float x) { return __builtin_amdgcn_exp2f(x); }
static __device__ __forceinline__ float fast_rcp(float x)  { return __builtin_amdgcn_rcpf(x); }

// fp32 -> bf16 bits, round-to-nearest-even (inputs are finite)
static __device__ __forceinline__ unsigned short f2b(float f) {
    unsigned int u = __float_as_uint(f);
    u += 0x7fffu + ((u >> 16) & 1u);
    return (unsigned short)(u >> 16);
}

// ---------------------------------------------------------------------------
// K1: fused input projections. blockIdx.y selects {q@Wq, k@Wk, k@Wv}.
// ---------------------------------------------------------------------------
#define TM 8
__global__ __launch_bounds__(256) void proj3_kernel(const float* __restrict__ Q,
                                                    const float* __restrict__ K,
                                                    const float* __restrict__ Wq,
                                                    const float* __restrict__ Wk,
                                                    const float* __restrict__ Wv,
                                                    float* __restrict__ qp,
                                                    float* __restrict__ kp,
                                                    float* __restrict__ vv) {
    const int which = blockIdx.y;
    const float* X = (which == 0) ? Q : K;
    const float* W = (which == 0) ? Wq : (which == 1) ? Wk : Wv;
    float* Y = (which == 0) ? qp : (which == 1) ? kp : vv;

    __shared__ __align__(16) float xs[TM][H_];
    const int t = threadIdx.x;
    const int r0 = blockIdx.x * TM;
    for (int idx = t; idx < TM * H_; idx += 256)
        xs[idx >> 8][idx & 255] = X[(size_t)(r0 + (idx >> 8)) * H_ + (idx & 255)];
    __syncthreads();

    float acc[TM];
#pragma unroll
    for (int r = 0; r < TM; ++r) acc[r] = 0.f;

    const float* wrow = W + (size_t)t * H_;
    for (int k = 0; k < H_; k += 4) {
        float4 w4 = *(const float4*)(wrow + k);
#pragma unroll
        for (int r = 0; r < TM; ++r) {
            acc[r] += w4.x * xs[r][k] + w4.y * xs[r][k + 1] +
                      w4.z * xs[r][k + 2] + w4.w * xs[r][k + 3];
        }
    }
#pragma unroll
    for (int r = 0; r < TM; ++r) Y[(size_t)(r0 + r) * H_ + t] = acc[r];
}

// single-projection variant for the output GEMM
__global__ __launch_bounds__(256) void proj_kernel(const float* __restrict__ X,
                                                   const float* __restrict__ W,
                                                   float* __restrict__ Y) {
    __shared__ __align__(16) float xs[TM][H_];
    const int t = threadIdx.x;
    const int r0 = blockIdx.x * TM;
    for (int idx = t; idx < TM * H_; idx += 256)
        xs[idx >> 8][idx & 255] = X[(size_t)(r0 + (idx >> 8)) * H_ + (idx & 255)];
    __syncthreads();

    float acc[TM];
#pragma unroll
    for (int r = 0; r < TM; ++r) acc[r] = 0.f;

    const float* wrow = W + (size_t)t * H_;
    for (int k = 0; k < H_; k += 4) {
        float4 w4 = *(const float4*)(wrow + k);
#pragma unroll
        for (int r = 0; r < TM; ++r) {
            acc[r] += w4.x * xs[r][k] + w4.y * xs[r][k + 1] +
                      w4.z * xs[r][k + 2] + w4.w * xs[r][k + 3];
        }
    }
#pragma unroll
    for (int r = 0; r < TM; ++r) Y[(size_t)(r0 + r) * H_ + t] = acc[r];
}

// ---------------------------------------------------------------------------
// K3: multi-head dot-product attention (flash-style over j-tiles of 128)
// ---------------------------------------------------------------------------
__global__ __launch_bounds__(256) void mh_attn_kernel(const float* __restrict__ qp,
                                                      const float* __restrict__ kp,
                                                      const float* __restrict__ vv,
                                                      float* __restrict__ ctx) {
    __shared__ __align__(16) float ks[128][36];
    __shared__ __align__(16) float vs[128][36];
    const int t = threadIdx.x;
    const int bh = blockIdx.x;
    const int b = bh >> 3, head = bh & 7;
    const int i0 = blockIdx.y * 32;
    const int r = t >> 3, sub = t & 7;
    const int i = i0 + r;
    const float rs = 0.17677669529663687f;   // 1/sqrt(32)
    const float C = 1.4426950408889634f;     // log2(e)

    const float* qptr = qp + ((size_t)(b * N_ + i)) * H_ + head * DH_;
    float4 q[8];
#pragma unroll
    for (int d = 0; d < 8; ++d) q[d] = *(const float4*)(qptr + d * 4);

    float mrun = -1e30f, lrun = 0.f;
    float4 o[8];
#pragma unroll
    for (int d = 0; d < 8; ++d) o[d] = make_float4(0.f, 0.f, 0.f, 0.f);

    for (int jt = 0; jt < 4; ++jt) {
        __syncthreads();
#pragma unroll
        for (int cc = 0; cc < 4; ++cc) {
            int cIdx = t + cc * 256;
            int jr = cIdx >> 3, d4 = cIdx & 7;
            size_t gofs = ((size_t)(b * M_ + jt * 128 + jr)) * H_ + head * DH_ + d4 * 4;
            *(float4*)(&ks[jr][d4 * 4]) = *(const float4*)(kp + gofs);
            *(float4*)(&vs[jr][d4 * 4]) = *(const float4*)(vv + gofs);
        }
        __syncthreads();

        float s16[16];
#pragma unroll
        for (int jj = 0; jj < 16; ++jj) {
            const float* kr = ks[sub + jj * 8];
            float a = 0.f;
#pragma unroll
            for (int d = 0; d < 8; ++d) {
                float4 kv = *(const float4*)(kr + d * 4);
                a += q[d].x * kv.x + q[d].y * kv.y + q[d].z * kv.z + q[d].w * kv.w;
            }
            s16[jj] = a * rs;
        }
        float tm = s16[0];
#pragma unroll
        for (int jj = 1; jj < 16; ++jj) tm = fmaxf(tm, s16[jj]);
        float mnew = fmaxf(mrun, tm);
        float corr = fast_exp2((mrun - mnew) * C);
        lrun *= corr;
#pragma unroll
        for (int d = 0; d < 8; ++d) {
            o[d].x *= corr; o[d].y *= corr; o[d].z *= corr; o[d].w *= corr;
        }
        mrun = mnew;
#pragma unroll
        for (int jj = 0; jj < 16; ++jj) {
            float p = fast_exp2((s16[jj] - mrun) * C);
            lrun += p;
            const float* vr = vs[sub + jj * 8];
#pragma unroll
            for (int d = 0; d < 8; ++d) {
                float4 vx = *(const float4*)(vr + d * 4);
                o[d].x = __builtin_fmaf(p, vx.x, o[d].x);
                o[d].y = __builtin_fmaf(p, vx.y, o[d].y);
                o[d].z = __builtin_fmaf(p, vx.z, o[d].z);
                o[d].w = __builtin_fmaf(p, vx.w, o[d].w);
            }
        }
    }

#pragma unroll
    for (int mask = 1; mask < 8; mask <<= 1) {
        float om = __shfl_xor(mrun, mask, 64);
        float ol = __shfl_xor(lrun, mask, 64);
        float Mx = fmaxf(mrun, om);
        float fa = fast_exp2((mrun - Mx) * C);
        float fb = fast_exp2((om - Mx) * C);
        lrun = lrun * fa + ol * fb;
#pragma unroll
        for (int d = 0; d < 8; ++d) {
            float ox = __shfl_xor(o[d].x, mask, 64);
            float oy = __shfl_xor(o[d].y, mask, 64);
            float oz = __shfl_xor(o[d].z, mask, 64);
            float ow = __shfl_xor(o[d].w, mask, 64);
            o[d].x = o[d].x * fa + ox * fb;
            o[d].y = o[d].y * fa + oy * fb;
            o[d].z = o[d].z * fa + oz * fb;
            o[d].w = o[d].w * fa + ow * fb;
        }
        mrun = Mx;
    }
    float inv = fast_rcp(lrun);
    float4 r4 = make_float4(0.f, 0.f, 0.f, 0.f);
#pragma unroll
    for (int d = 0; d < 8; ++d) if (sub == d) r4 = o[d];
    r4.x *= inv; r4.y *= inv; r4.z *= inv; r4.w *= inv;
    *(float4*)(ctx + ((size_t)(b * N_ + i)) * H_ + head * DH_ + sub * 4) = r4;
}

// ---------------------------------------------------------------------------
// K2: additive-attention branch — R12 structure with sync-overhead removal:
//  (a) ping-pong qrow[2]: tile t reads buf p while wave0 writes t+1's q into
//      buf p^1 -> ONE __syncthreads per tile (was two).
//  (b) wave0 issues t+1's q global load at the TOP of tile t's k-loop; the
//      load latency hides under ~8 us of compute; LDS write happens post-loop.
//  (c) epilogue exp in-place in acc (p[16] eliminated).
// Math identical to R12 (q pre-scaled 2*log2e, Wv pre-scaled log2e).
// ---------------------------------------------------------------------------
#define BM2 256
#define TILES_TOTAL 2048
#define K2_BLOCKS 256

__global__ __launch_bounds__(512, 2) void addattn_kernel(const float* __restrict__ qp,
                                                         const float* __restrict__ kp,
                                                         const float* __restrict__ Wv,
                                                         float* __restrict__ attn) {
    __shared__ __align__(16) unsigned short wv_s[H_ * H_];  // 128 KB swizzled bf16 (pre-scaled by C)
    __shared__ __align__(16) float qrow[2][H_];             // 2 KB ping-pong (pre-scaled by 2*log2e)

    const int t = threadIdx.x;
    const int lane = t & 63;
    const int w = t >> 6;        // wave 0..7
    const int li = lane & 15;
    const int kq = lane >> 4;    // 0..3
    const int wrow0 = w * 32;
    const float C = 1.4426950408889634f;
    const float L2E2 = 2.885390081777927f;   // 2*log2(e)

    // ---- stage C*Wv as bf16 with 16B-slot XOR swizzle (key = o&15) ----
#pragma unroll
    for (int it = 0; it < 16; ++it) {
        int sIdx = t + it * 512;          // 16B-slot index 0..8191
        int o = sIdx >> 5;
        int slot = sIdx & 31;
        const float* src = Wv + (size_t)o * H_ + slot * 8;
        float4 a = *(const float4*)(src);
        float4 bq = *(const float4*)(src + 4);
        union { unsigned short us[8]; uint4 v; } pk;
        pk.us[0] = f2b(a.x * C);  pk.us[1] = f2b(a.y * C);  pk.us[2] = f2b(a.z * C);  pk.us[3] = f2b(a.w * C);
        pk.us[4] = f2b(bq.x * C); pk.us[5] = f2b(bq.y * C); pk.us[6] = f2b(bq.z * C); pk.us[7] = f2b(bq.w * C);
        int dslot = slot ^ (o & 15);
        *(uint4*)(wv_s + (size_t)o * 256 + dslot * 8) = pk.v;
    }

    int tile = blockIdx.x;

    // prologue: wave0 stages tile0's q into qrow[0]; preload tile0 kp kk=0
    if (t < 64) {
        f32x4 qv = *(const f32x4*)(qp + ((size_t)((tile >> 10) * N_ + ((tile >> 1) & (N_ - 1)))) * H_ + t * 4);
        qv *= L2E2;
        *(f32x4*)(&qrow[0][t * 4]) = qv;
    }
    float4 cur[2][2];
    {
        const int b = tile >> 10;
        const int j0 = (tile & 1) * BM2;
#pragma unroll
        for (int rf = 0; rf < 2; ++rf) {
            const int jl = wrow0 + rf * 16 + li;
            const float* kr = kp + ((size_t)(b * M_ + j0 + jl)) * H_ + kq * 8;
            cur[rf][0] = *(const float4*)(kr);
            cur[rf][1] = *(const float4*)(kr + 4);
        }
    }
    __syncthreads();   // wv_s + qrow[0] visible

    int tp = 0;
    for (; tile < TILES_TOTAL; tile += K2_BLOCKS) {
        const int b = tile >> 10;                 // tile / 1024
        const int j0 = (tile & 1) * BM2;
        const bool has_next = (tile + K2_BLOCKS < TILES_TOTAL);

        // (b) wave0 issues NEXT tile's q load now; completes under the k-loop
        f32x4 qnext;
        if (has_next && t < 64) {
            const int nt = tile + K2_BLOCKS;
            qnext = *(const f32x4*)(qp + ((size_t)((nt >> 10) * N_ + ((nt >> 1) & (N_ - 1)))) * H_ + t * 4);
        }

        f32x4 acc[2][16];
#pragma unroll
        for (int rf = 0; rf < 2; ++rf)
#pragma unroll
            for (int c = 0; c < 16; ++c) acc[rf][c] = (f32x4){0.f, 0.f, 0.f, 0.f};

#pragma unroll
        for (int kk = 0; kk < 8; ++kk) {
            float4 nxt[2][2];
            if (kk < 7) {
#pragma unroll
                for (int rf = 0; rf < 2; ++rf) {
                    const int jl = wrow0 + rf * 16 + li;
                    const float* kr = kp + ((size_t)(b * M_ + j0 + jl)) * H_ + (kk + 1) * 32 + kq * 8;
                    nxt[rf][0] = *(const float4*)(kr);
                    nxt[rf][1] = *(const float4*)(kr + 4);
                }
            }
            f32x4 qs0 = *(const f32x4*)(&qrow[tp][kk * 32 + kq * 8]);
            f32x4 qs1 = *(const f32x4*)(&qrow[tp][kk * 32 + kq * 8 + 4]);

            bf16x8 afr[2];
#pragma unroll
            for (int rf = 0; rf < 2; ++rf) {
                float xin[8] = {
                    __builtin_fmaf(cur[rf][0].x, L2E2, qs0[0]),
                    __builtin_fmaf(cur[rf][0].y, L2E2, qs0[1]),
                    __builtin_fmaf(cur[rf][0].z, L2E2, qs0[2]),
                    __builtin_fmaf(cur[rf][0].w, L2E2, qs0[3]),
                    __builtin_fmaf(cur[rf][1].x, L2E2, qs1[0]),
                    __builtin_fmaf(cur[rf][1].y, L2E2, qs1[1]),
                    __builtin_fmaf(cur[rf][1].z, L2E2, qs1[2]),
                    __builtin_fmaf(cur[rf][1].w, L2E2, qs1[3])};
                union { unsigned short us[8]; bf16x8 v; } au;
#pragma unroll
                for (int e = 0; e < 8; ++e) {
                    float e2 = fast_exp2(xin[e]);
                    float th = __builtin_fmaf(-2.0f, fast_rcp(e2 + 1.0f), 1.0f);
                    au.us[e] = f2b(th);
                }
                afr[rf] = au.v;
            }

#pragma unroll
            for (int c = 0; c < 16; ++c) {
                const int o = c * 16 + li;
                const int slot = (kk * 4 + kq) ^ (o & 15);
                bf16x8 bfr = *(const bf16x8*)(wv_s + (size_t)o * 256 + slot * 8);
                acc[0][c] = __builtin_amdgcn_mfma_f32_16x16x32_bf16(afr[0], bfr, acc[0][c], 0, 0, 0);
                acc[1][c] = __builtin_amdgcn_mfma_f32_16x16x32_bf16(afr[1], bfr, acc[1][c], 0, 0, 0);
            }
            if (kk < 7) {
#pragma unroll
                for (int rf = 0; rf < 2; ++rf) { cur[rf][0] = nxt[rf][0]; cur[rf][1] = nxt[rf][1]; }
            }
        }

        // (a) wave0 writes NEXT tile's q into the OTHER qrow buffer (no
        // barrier needed: other waves read qrow[tp] only)
        if (has_next && t < 64) {
            qnext *= L2E2;
            *(f32x4*)(&qrow[tp ^ 1][t * 4]) = qnext;
        }

        // prefetch next tile's kp (kk=0) BEFORE the epilogue stores
        if (has_next) {
            const int nt = tile + K2_BLOCKS;
            const int nb = nt >> 10;
            const int nj0 = (nt & 1) * BM2;
#pragma unroll
            for (int rf = 0; rf < 2; ++rf) {
                const int jl = wrow0 + rf * 16 + li;
                const float* kr = kp + ((size_t)(nb * M_ + nj0 + jl)) * H_ + kq * 8;
                cur[rf][0] = *(const float4*)(kr);
                cur[rf][1] = *(const float4*)(kr + 4);
            }
        }

        // ---- epilogue: softmax (p = exp2(acc) in-place; bounded scores, no
        // max subtraction), scalar dword nt stores (full 64B line per
        // 16-lane group per instruction) ----
        const size_t prow = (size_t)tile * BM2;
#pragma unroll
        for (int rf = 0; rf < 2; ++rf) {
#pragma unroll
            for (int v = 0; v < 4; ++v) {
                float rsum = 0.f;
#pragma unroll
                for (int c = 0; c < 16; ++c) {
                    float e = fast_exp2(acc[rf][c][v]);
                    acc[rf][c][v] = e;
                    rsum += e;
                }
#pragma unroll
                for (int mask = 1; mask < 16; mask <<= 1)
                    rsum += __shfl_xor(rsum, mask, 64);
                const float inv = fast_rcp(rsum);
                const int jl = wrow0 + rf * 16 + kq * 4 + v;
                float* dst = attn + (prow + jl) * (size_t)H_ + li;
#pragma unroll
                for (int c = 0; c < 16; ++c)
                    __builtin_nontemporal_store(acc[rf][c][v] * inv, dst + c * 16);
            }
        }

        __syncthreads();   // ONE barrier/tile: qrow[tp^1] visible; stores drain
        tp ^= 1;
    }
}

// ---------------------------------------------------------------------------
extern "C" void kernel_launch(void* const* d_in, const int* in_sizes, int n_in,
                              void* d_out, int out_size, void* d_ws, size_t ws_size,
                              hipStream_t stream) {
    (void)in_sizes; (void)n_in; (void)out_size; (void)ws_size;
    const float* queries = (const float*)d_in[0];
    const float* keys    = (const float*)d_in[1];
    const float* Wq = (const float*)d_in[3];
    const float* Wk = (const float*)d_in[4];
    const float* Wv = (const float*)d_in[5];
    const float* Wo = (const float*)d_in[6];

    float* out0 = (float*)d_out;                               // (B, n, H)
    float* attn = (float*)d_out + (size_t)B_ * N_ * H_;        // (B, n, m, H)

    float* ws  = (float*)d_ws;
    float* qp  = ws;                 // 262144 f
    float* kp  = ws + 262144;        // 262144 f
    float* vv  = ws + 524288;        // 262144 f
    float* ctx = ws + 786432;        // 262144 f

    proj3_kernel<<<dim3(128, 3), dim3(256), 0, stream>>>(queries, keys, Wq, Wk, Wv, qp, kp, vv);
    mh_attn_kernel<<<dim3(16, 16), dim3(256), 0, stream>>>(qp, kp, vv, ctx);
    proj_kernel<<<dim3(128), dim3(256), 0, stream>>>(ctx, Wo, out0);
    addattn_kernel<<<dim3(K2_BLOCKS), dim3(512), 0, stream>>>(qp, kp, Wv, attn);
}